// Round 15
// baseline (953.883 us; speedup 1.0000x reference)
//
#include <hip/hip_runtime.h>
#include <hip/hip_bf16.h>
#include <math.h>

#define NN 100000
#define NNP 100096          // padded to 782*128
#define NE 300000
#define HID 128
#define EMB 64
#define NG 4096
#define DEG_CAP 32
#define XS 512              // X row stride in elements

typedef __bf16 bf16x8 __attribute__((ext_vector_type(8)));
typedef float  f32x16 __attribute__((ext_vector_type(16)));
typedef short  short8 __attribute__((ext_vector_type(8)));

typedef const __attribute__((address_space(1))) unsigned int* gas_u32;
typedef __attribute__((address_space(3))) unsigned int* las_u32;

__device__ __forceinline__ void gload16(const void* g, void* l) {
    __builtin_amdgcn_global_load_lds((gas_u32)g, (las_u32)l, 16, 0, 0);
}

__device__ __forceinline__ float bf2f(unsigned short u) {
    unsigned int x = ((unsigned int)u) << 16;
    return __builtin_bit_cast(float, x);
}
__device__ __forceinline__ unsigned short f2bf(float f) {
    unsigned int x = __builtin_bit_cast(unsigned int, f);
    unsigned int r = x + 0x7fff + ((x >> 16) & 1);
    return (unsigned short)(r >> 16);
}
__device__ __forceinline__ float sigm(float x) { return 1.f / (1.f + __expf(-x)); }

#define MFMA(A, B, C) __builtin_amdgcn_mfma_f32_32x32x16_bf16( \
    __builtin_bit_cast(bf16x8, A), __builtin_bit_cast(bf16x8, B), C, 0, 0, 0)

// ---------------------------------------------------------------------------
// h init: node_features f32 -> Y bf16 [NNP][128]; pad rows zeroed.
// ---------------------------------------------------------------------------
__global__ __launch_bounds__(256) void k_init(const float* __restrict__ nf,
                                              unsigned short* __restrict__ Y) {
    int id = blockIdx.x * 256 + threadIdx.x;   // NNP*HID
    int n = id >> 7, c = id & 127;
    Y[(long)n * HID + c] = (n < NN) ? f2bf(nf[(long)n * HID + c]) : (unsigned short)0;
}

// ---------------------------------------------------------------------------
// CSR build (deg true counts; csr capped at DEG_CAP)
// ---------------------------------------------------------------------------
__global__ __launch_bounds__(256) void k_build_csr(const int* __restrict__ ei,
                                                   int* __restrict__ deg,
                                                   int* __restrict__ csr) {
    int id = blockIdx.x * 256 + threadIdx.x;
    if (id >= 3 * NE) return;
    int t = id / NE;
    int i = id - t * NE;
    int src = ei[(t * 2 + 0) * NE + i];
    int dst = ei[(t * 2 + 1) * NE + i];
    int p = atomicAdd(&deg[t * NN + dst], 1);
    if (p < DEG_CAP) csr[((long)t * NN + dst) * DEG_CAP + p] = src;
}

__global__ __launch_bounds__(256) void k_pack_deg(const int* __restrict__ deg,
                                                  int4* __restrict__ degp) {
    int n = blockIdx.x * 256 + threadIdx.x;
    if (n >= NNP) return;
    int4 v; v.x = 0; v.y = 0; v.z = 0; v.w = 0;
    if (n < NN) { v.x = deg[n]; v.y = deg[NN + n]; v.z = deg[2 * NN + n]; }
    degp[n] = v;
}

// ---------------------------------------------------------------------------
// Bf: FRAGMENT-ORDERED weights. n' = c*4 + sec (sec-minor). For MFMA
// 32x32x16 B-operand, lane = kg*32 + nl supplies B[n' = nb*32+nl]
// [k = k16*16 + kg*8 + e]. Fragment (nb,k16) = contiguous 1KB.
// K layout: k<384 -> A_cat (Wm @ Wih_sec^T), k>=384 -> h (Whh_sec).
// ---------------------------------------------------------------------------
__global__ __launch_bounds__(512) void k_build_w(const float* __restrict__ Wmsg,
                                                 const float* __restrict__ Wih,
                                                 const float* __restrict__ Whh,
                                                 unsigned short* __restrict__ Bf) {
    int np = blockIdx.x;       // 0..511 permuted col
    int k = threadIdx.x;       // 0..511
    int c = np >> 2, sec = np & 3;
    float v = 0.f;
    if (k < 384) {
        if (sec < 3) {
            int t = k >> 7, kk = k & 127;
            const float* wm = Wmsg + ((long)t * HID + kk) * HID;
            const float* wi = Wih + (long)(sec * HID + c) * HID;
            float s = 0.f;
            for (int j = 0; j < HID; j++) s += wm[j] * wi[j];
            v = s;
        }
    } else {
        int kk = k - 384;
        if (sec == 0)      v = Whh[(long)c * HID + kk];
        else if (sec == 1) v = Whh[(long)(HID + c) * HID + kk];
        else if (sec == 3) v = Whh[(long)(2 * HID + c) * HID + kk];
    }
    int nb = np >> 5, nl = np & 31;
    int k16 = k >> 4, kgg = (k >> 3) & 1, e = k & 7;
    Bf[((((nb * 32 + k16) * 2 + kgg) * 32 + nl) << 3) + e] = f2bf(v);
}

__global__ __launch_bounds__(512) void k_build_bias(const float* __restrict__ bih,
                                                    const float* __restrict__ bhh,
                                                    const float* __restrict__ bmsg,
                                                    const float* __restrict__ Wih,
                                                    float* __restrict__ bbig,
                                                    float* __restrict__ Bdeg) {
    int np = threadIdx.x;      // 0..511 permuted
    int c = np >> 2, sec = np & 3;
    float b;
    if (sec == 0)      b = bih[c] + bhh[c];
    else if (sec == 1) b = bih[HID + c] + bhh[HID + c];
    else if (sec == 2) b = bih[2 * HID + c];
    else               b = bhh[2 * HID + c];
    bbig[np] = b;
    for (int t = 0; t < 3; t++) {
        float s = 0.f;
        if (sec < 3) {
            const float* wi = Wih + (long)(sec * HID + c) * HID;
            const float* bm = bmsg + t * HID;
            for (int j = 0; j < HID; j++) s += bm[j] * wi[j];
        }
        Bdeg[t * 512 + np] = s;
    }
}

// ---------------------------------------------------------------------------
// Aggregate: one WAVE per node, gather from compact Y [n][128], write A_cat
// into X cols 0..383 AND copy h (Y row) into X cols 384..511.
// ---------------------------------------------------------------------------
__global__ __launch_bounds__(256) void k_agg(const unsigned short* __restrict__ Y,
                                             unsigned short* __restrict__ X,
                                             const int* __restrict__ deg,
                                             const int* __restrict__ csr) {
    const int lane = threadIdx.x & 63;
    const long n = (long)blockIdx.x * 4 + (threadIdx.x >> 6);
    const int g = lane >> 4;
    const int c16 = lane & 15;
    const int l31 = lane & 31;

    int d[3], il[3];
#pragma unroll
    for (int t = 0; t < 3; t++) {
        int dt = deg[t * NN + n];
        d[t] = dt > DEG_CAP ? DEG_CAP : dt;
        il[t] = csr[((long)t * NN + n) * DEG_CAP + l31];
    }
#pragma unroll
    for (int t = 0; t < 3; t++) {
        float acc[8] = {0.f, 0.f, 0.f, 0.f, 0.f, 0.f, 0.f, 0.f};
        int rounds = (d[t] + 3) >> 2;
        for (int r = 0; r < rounds; r++) {
            int j = r * 4 + g;
            int idx = __shfl(il[t], j & 31);
            if (j < d[t]) {
                short8 v = *(const short8*)(Y + (long)idx * HID + c16 * 8);
#pragma unroll
                for (int q = 0; q < 8; q++) acc[q] += bf2f((unsigned short)v[q]);
            }
        }
#pragma unroll
        for (int q = 0; q < 8; q++) {
            acc[q] += __shfl_xor(acc[q], 16);
            acc[q] += __shfl_xor(acc[q], 32);
        }
        if (g == 0) {
            short8 o;
#pragma unroll
            for (int q = 0; q < 8; q++) o[q] = (short)f2bf(acc[q]);
            *(short8*)(X + n * XS + t * HID + c16 * 8) = o;
        }
    }
    if (g == 1) {   // h copy: Y row -> X cols 384..511
        short8 v = *(const short8*)(Y + n * HID + c16 * 8);
        *(short8*)(X + n * XS + 384 + c16 * 8) = v;
    }
}

// ---------------------------------------------------------------------------
// Fused GRU step, v3 (B-convoy fix): [A_cat|h] (K=512) x Bf (N=512) + gates.
// BM=128, BN=512, 8 waves, wave tile 128x64: acc[4M][2N] = 128 AGPR ->
// MFMA:B-load ratio 4:1 (R7/R11/R12 all ran 2:1; B-load rate was the convoy).
// Per-CU per round: MFMA 516 cy > ds_read 384 > B-L2 292 -> MFMA-bound.
// A full-K in 128KB LDS (dynamic): stage half0 -> barrier -> fire half1 ->
// 16 k-steps -> drain-free barrier (half1 landed long ago) -> 16 k-steps.
// ZERO barriers inside each run; 1 block/CU is fine (no lockstep points).
// B: depth-2 explicit prefetch, fragment-ordered coalesced 1KB wave-loads.
// Epilogue v2 x 4 quarters (32 rows each) through EX[32][516] overlay.
// ---------------------------------------------------------------------------
__global__ __launch_bounds__(512, 2) void k_gru_mfma(
        const unsigned short* __restrict__ X,
        const unsigned short* __restrict__ Y,
        unsigned short* __restrict__ Yw,
        const unsigned short* __restrict__ Bf,
        const float* __restrict__ bbig, const float* __restrict__ Bdeg,
        const int4* __restrict__ degp) {
    extern __shared__ char lds[];   // 131072 B: A frags (128 x 1KB); EX overlay

    const int tid = threadIdx.x;
    const int lane = tid & 63;
    const int wv = tid >> 6;        // 0..7 = N slot (64 cols each)
    const int r31 = lane & 31;
    const int kg = lane >> 5;
    const long row0 = (long)blockIdx.x * 128;

    f32x16 acc[4][2];               // [mt 32-row quarter][ct 32-col half]
#pragma unroll
    for (int i = 0; i < 4; i++)
#pragma unroll
        for (int j = 0; j < 2; j++) acc[i][j] = (f32x16)(0.0f);

    // A staging: half H, local frag f = k16l*4 + mt at lds[(H*64+f)*1024];
    // lane kg*32+r31 holds A[row0 + mt*32 + r31][k16g*16 + kg*8 .. +8].
    const char* base = (const char*)X + (row0 + r31) * 1024 + kg * 16;
#define STAGE_A(H)                                                            \
    {                                                                         \
        _Pragma("unroll")                                                     \
        for (int jj = 0; jj < 8; jj++) {                                      \
            const int f = wv * 8 + jj;                                        \
            gload16(base + (long)(f & 3) * 32768 + ((H) * 16 + (f >> 2)) * 32,\
                    lds + ((H) * 64 + f) * 1024);                             \
        }                                                                     \
    }

    const unsigned short* pB0 = Bf + (wv * 2 + 0) * 16384 + lane * 8;
    const unsigned short* pB1 = Bf + (wv * 2 + 1) * 16384 + lane * 8;

    STAGE_A(0);
    __syncthreads();                // half-0 ready
    STAGE_A(1);                     // fire-and-forget; lands during loop 1
#undef STAGE_A

    // depth-2 B prefetch slots (even/odd k16)
    short8 pe0 = *(const short8*)(pB0);
    short8 pe1 = *(const short8*)(pB1);
    short8 po0 = *(const short8*)(pB0 + 512);
    short8 po1 = *(const short8*)(pB1 + 512);

#define KSTEP(K16, B0, B1)                                                    \
    {                                                                         \
        const char* fb = lds + (((K16) >> 4) * 64 + ((K16) & 15) * 4) * 1024  \
                         + lane * 16;                                         \
        short8 a0 = *(const short8*)(fb);                                     \
        short8 a1 = *(const short8*)(fb + 1024);                              \
        short8 a2 = *(const short8*)(fb + 2048);                              \
        short8 a3 = *(const short8*)(fb + 3072);                              \
        acc[0][0] = MFMA(a0, B0, acc[0][0]);                                  \
        acc[0][1] = MFMA(a0, B1, acc[0][1]);                                  \
        acc[1][0] = MFMA(a1, B0, acc[1][0]);                                  \
        acc[1][1] = MFMA(a1, B1, acc[1][1]);                                  \
        acc[2][0] = MFMA(a2, B0, acc[2][0]);                                  \
        acc[2][1] = MFMA(a2, B1, acc[2][1]);                                  \
        acc[3][0] = MFMA(a3, B0, acc[3][0]);                                  \
        acc[3][1] = MFMA(a3, B1, acc[3][1]);                                  \
    }

#pragma unroll
    for (int it = 0; it < 8; it++) {        // k16 0..15 (half 0)
        const int k0 = 2 * it;
        KSTEP(k0, pe0, pe1);
        pe0 = *(const short8*)(pB0 + (k0 + 2) * 512);
        pe1 = *(const short8*)(pB1 + (k0 + 2) * 512);
        KSTEP(k0 + 1, po0, po1);
        po0 = *(const short8*)(pB0 + (k0 + 3) * 512);
        po1 = *(const short8*)(pB1 + (k0 + 3) * 512);
    }
    __syncthreads();                // half-1 ready (issued 16 k-steps ago)
#pragma unroll
    for (int it = 8; it < 16; it++) {       // k16 16..31 (half 1)
        const int k0 = 2 * it;
        KSTEP(k0, pe0, pe1);
        if (it < 15) {
            pe0 = *(const short8*)(pB0 + (k0 + 2) * 512);
            pe1 = *(const short8*)(pB1 + (k0 + 2) * 512);
        }
        KSTEP(k0 + 1, po0, po1);
        if (it < 15) {
            po0 = *(const short8*)(pB0 + (k0 + 3) * 512);
            po1 = *(const short8*)(pB1 + (k0 + 3) * 512);
        }
    }
#undef KSTEP

    // ---- epilogue: 4 quarters of 32 rows; EX = [32][516] f32 overlay ----
    float* EX = (float*)lds;
    const int ch = tid & 127;               // channel 0..127
    const int r5b = tid >> 7;               // 0..3
    const float4 bb  = *(const float4*)(bbig + ch * 4);
    const float4 q0v = *(const float4*)(Bdeg + ch * 4);
    const float4 q1v = *(const float4*)(Bdeg + 512 + ch * 4);
    const float4 q2v = *(const float4*)(Bdeg + 1024 + ch * 4);

#pragma unroll
    for (int q = 0; q < 4; q++) {
        __syncthreads();
#pragma unroll
        for (int ct = 0; ct < 2; ct++) {
            const int col = wv * 64 + ct * 32 + r31;
#pragma unroll
            for (int reg = 0; reg < 16; reg++) {
                int r5 = (reg & 3) + 8 * (reg >> 2) + 4 * kg;
                EX[r5 * 516 + col] = acc[q][ct][reg];
            }
        }
        __syncthreads();
#pragma unroll
        for (int i = 0; i < 8; i++) {
            const int r5 = r5b + 4 * i;     // 0..31
            long grow = row0 + q * 32 + r5;
            int4 dg = degp[grow];
            float dgx = (float)dg.x, dgy = (float)dg.y, dgz = (float)dg.z;
            float4 v = *(const float4*)(EX + r5 * 516 + ch * 4);
            float Sr = v.x + bb.x + dgx * q0v.x + dgy * q1v.x + dgz * q2v.x;
            float Sz = v.y + bb.y + dgx * q0v.y + dgy * q1v.y + dgz * q2v.y;
            float In = v.z + bb.z + dgx * q0v.z + dgy * q1v.z + dgz * q2v.z;
            float Hn = v.w + bb.w;          // sec3 deg-bias is 0 by construction
            float rr = sigm(Sr);
            float zz = sigm(Sz);
            float tt = In + rr * Hn;
            float ee = __expf(2.f * tt);
            float nn = 1.f - 2.f / (ee + 1.f);
            float hv = (1.f - zz) * nn + zz * bf2f(Y[grow * HID + ch]);
            Yw[grow * HID + ch] = f2bf(hv);
        }
    }
}

// ---------------------------------------------------------------------------
// Readout: out[g] += sigmoid(h@Wg.T+bg) * (h@Wp.T+bp). h from Y bf16.
// ---------------------------------------------------------------------------
__global__ __launch_bounds__(256) void k_readout(const unsigned short* __restrict__ Y,
                                                 const int* __restrict__ n2g,
                                                 const float* __restrict__ Wp,
                                                 const float* __restrict__ bp,
                                                 const float* __restrict__ Wg,
                                                 const float* __restrict__ bg,
                                                 float* __restrict__ out) {
    __shared__ float hs[32][132];
    __shared__ float Ws[64][129];
    int tid = threadIdx.x;
    long row0 = (long)blockIdx.x * 32;
    int rg = tid >> 5, cg = tid & 31;
    float acc[4][4];
#pragma unroll
    for (int r = 0; r < 4; r++)
#pragma unroll
        for (int c = 0; c < 4; c++) acc[r][c] = 0.f;

#pragma unroll
    for (int p = 0; p < 2; p++) {
        int e = p * 256 + tid;
        int r = e >> 4, c8 = e & 15;
        short8 v = *(const short8*)(Y + (row0 + r) * HID + c8 * 8);
#pragma unroll
        for (int j = 0; j < 8; j++) hs[r][c8 * 8 + j] = bf2f((unsigned short)v[j]);
    }
    for (int kc = 0; kc < 128; kc += 64) {
        __syncthreads();
#pragma unroll
        for (int p = 0; p < 8; p++) {
            int idx = p * 256 + tid;
            int j = idx >> 4, q = idx & 15;
            const float* Wsrc = (j < 64) ? Wp : Wg;
            float4 w = *(const float4*)&Wsrc[(j & 63) * HID + kc + q * 4];
            Ws[q * 4 + 0][j] = w.x;
            Ws[q * 4 + 1][j] = w.y;
            Ws[q * 4 + 2][j] = w.z;
            Ws[q * 4 + 3][j] = w.w;
        }
        __syncthreads();
#pragma unroll 8
        for (int k = 0; k < 64; k++) {
            float a[4], w[4];
#pragma unroll
            for (int r = 0; r < 4; r++) a[r] = hs[rg * 4 + r][kc + k];
#pragma unroll
            for (int c = 0; c < 4; c++) w[c] = Ws[k][cg + 32 * c];
#pragma unroll
            for (int r = 0; r < 4; r++)
#pragma unroll
                for (int c = 0; c < 4; c++) acc[r][c] += a[r] * w[c];
        }
    }
#pragma unroll
    for (int r = 0; r < 4; r++) {
        long row = row0 + rg * 4 + r;
        if (row < NN) {
            int g = n2g[row];
            float pv0 = acc[r][0] + bp[cg];
            float pv1 = acc[r][1] + bp[cg + 32];
            float gv0 = acc[r][2] + bg[cg];
            float gv1 = acc[r][3] + bg[cg + 32];
            atomicAdd(&out[g * EMB + cg],      pv0 * sigm(gv0));
            atomicAdd(&out[g * EMB + cg + 32], pv1 * sigm(gv1));
        }
    }
}

// ---------------------------------------------------------------------------
extern "C" void kernel_launch(void* const* d_in, const int* in_sizes, int n_in,
                              void* d_out, int out_size, void* d_ws, size_t ws_size,
                              hipStream_t stream) {
    const float* node_features = (const float*)d_in[0];
    const int*   edge_index    = (const int*)d_in[1];
    const int*   n2g           = (const int*)d_in[2];
    const float* W_msg         = (const float*)d_in[3];
    const float* b_msg         = (const float*)d_in[4];
    const float* W_ih          = (const float*)d_in[5];
    const float* W_hh          = (const float*)d_in[6];
    const float* b_ih          = (const float*)d_in[7];
    const float* b_hh          = (const float*)d_in[8];
    const float* W_proj        = (const float*)d_in[9];
    const float* b_proj        = (const float*)d_in[10];
    const float* W_gate        = (const float*)d_in[11];
    const float* b_gate        = (const float*)d_in[12];

    char* ws = (char*)d_ws;
    unsigned short* X    = (unsigned short*)(ws);                 // 102,498,304 B
    unsigned short* Y    = (unsigned short*)(ws + 102498304);     //  25,624,576 B
    unsigned short* Bf   = (unsigned short*)(ws + 128122880);     //     524,288 B
    float*          bbig = (float*)         (ws + 128647168);     //       2,048 B
    float*          Bdeg = (float*)         (ws + 128649216);     //       6,144 B
    int4*           degp = (int4*)          (ws + 128655360);     //   1,601,536 B
    int*            deg  = (int*)           (ws + 130256896);     //   1,200,000 B
    int*            csr  = (int*)           (ws + 131456896);     //  38,400,000 B -> 169,856,896

    float* out = (float*)d_out;

    hipMemsetAsync(out, 0, (size_t)NG * EMB * sizeof(float), stream);
    hipMemsetAsync(deg, 0, (size_t)3 * NN * sizeof(int), stream);

    k_init<<<dim3((NNP * HID) / 256), dim3(256), 0, stream>>>(node_features, Y);
    k_build_csr<<<dim3((3 * NE + 255) / 256), dim3(256), 0, stream>>>(edge_index, deg, csr);
    k_pack_deg<<<dim3(NNP / 256), dim3(256), 0, stream>>>(deg, degp);
    k_build_w<<<dim3(512), dim3(512), 0, stream>>>(W_msg, W_ih, W_hh, Bf);
    k_build_bias<<<dim3(1), dim3(512), 0, stream>>>(b_ih, b_hh, b_msg, W_ih, bbig, Bdeg);

    for (int step = 0; step < 4; step++) {
        k_agg<<<dim3(NN / 4), dim3(256), 0, stream>>>(Y, X, deg, csr);
        k_gru_mfma<<<dim3(NNP / 128), dim3(512), 131072, stream>>>(X, Y, Y, Bf,
                                                                   bbig, Bdeg, degp);
    }
    k_readout<<<dim3(NN / 32), dim3(256), 0, stream>>>(Y, n2g, W_proj, b_proj,
                                                       W_gate, b_gate, out);
}

// Round 16
// 877.997 us; speedup vs baseline: 1.0864x; 1.0864x over previous
//
#include <hip/hip_runtime.h>
#include <hip/hip_bf16.h>
#include <math.h>

#define NN 100000
#define NNP 100096          // padded to 782*128
#define NE 300000
#define HID 128
#define EMB 64
#define NG 4096
#define DEG_CAP 32
#define XS 512              // X row stride in elements

typedef __bf16 bf16x8 __attribute__((ext_vector_type(8)));
typedef float  f32x16 __attribute__((ext_vector_type(16)));
typedef short  short8 __attribute__((ext_vector_type(8)));

typedef const __attribute__((address_space(1))) unsigned int* gas_u32;
typedef __attribute__((address_space(3))) unsigned int* las_u32;

__device__ __forceinline__ void gload16(const void* g, void* l) {
    __builtin_amdgcn_global_load_lds((gas_u32)g, (las_u32)l, 16, 0, 0);
}

__device__ __forceinline__ float bf2f(unsigned short u) {
    unsigned int x = ((unsigned int)u) << 16;
    return __builtin_bit_cast(float, x);
}
__device__ __forceinline__ unsigned short f2bf(float f) {
    unsigned int x = __builtin_bit_cast(unsigned int, f);
    unsigned int r = x + 0x7fff + ((x >> 16) & 1);
    return (unsigned short)(r >> 16);
}
__device__ __forceinline__ float sigm(float x) { return 1.f / (1.f + __expf(-x)); }

#define MFMA(A, B, C) __builtin_amdgcn_mfma_f32_32x32x16_bf16( \
    __builtin_bit_cast(bf16x8, A), __builtin_bit_cast(bf16x8, B), C, 0, 0, 0)

// ---------------------------------------------------------------------------
// h init: node_features f32 -> Y bf16 [NNP][128]; pad rows zeroed.
// ---------------------------------------------------------------------------
__global__ __launch_bounds__(256) void k_init(const float* __restrict__ nf,
                                              unsigned short* __restrict__ Y) {
    int id = blockIdx.x * 256 + threadIdx.x;   // NNP*HID
    int n = id >> 7, c = id & 127;
    Y[(long)n * HID + c] = (n < NN) ? f2bf(nf[(long)n * HID + c]) : (unsigned short)0;
}

// ---------------------------------------------------------------------------
// CSR build (deg true counts; csr capped at DEG_CAP)
// ---------------------------------------------------------------------------
__global__ __launch_bounds__(256) void k_build_csr(const int* __restrict__ ei,
                                                   int* __restrict__ deg,
                                                   int* __restrict__ csr) {
    int id = blockIdx.x * 256 + threadIdx.x;
    if (id >= 3 * NE) return;
    int t = id / NE;
    int i = id - t * NE;
    int src = ei[(t * 2 + 0) * NE + i];
    int dst = ei[(t * 2 + 1) * NE + i];
    int p = atomicAdd(&deg[t * NN + dst], 1);
    if (p < DEG_CAP) csr[((long)t * NN + dst) * DEG_CAP + p] = src;
}

__global__ __launch_bounds__(256) void k_pack_deg(const int* __restrict__ deg,
                                                  int4* __restrict__ degp) {
    int n = blockIdx.x * 256 + threadIdx.x;
    if (n >= NNP) return;
    int4 v; v.x = 0; v.y = 0; v.z = 0; v.w = 0;
    if (n < NN) { v.x = deg[n]; v.y = deg[NN + n]; v.z = deg[2 * NN + n]; }
    degp[n] = v;
}

// ---------------------------------------------------------------------------
// Bf: FRAGMENT-ORDERED weights. n' = c*4 + sec (sec-minor). For MFMA
// 32x32x16 B-operand, lane = kg*32 + nl supplies B[n' = nb*32+nl]
// [k = k16*16 + kg*8 + e]. Fragment (nb,k16) = contiguous 1KB.
// K layout: k<384 -> A_cat (Wm @ Wih_sec^T), k>=384 -> h (Whh_sec).
// ---------------------------------------------------------------------------
__global__ __launch_bounds__(512) void k_build_w(const float* __restrict__ Wmsg,
                                                 const float* __restrict__ Wih,
                                                 const float* __restrict__ Whh,
                                                 unsigned short* __restrict__ Bf) {
    int np = blockIdx.x;       // 0..511 permuted col
    int k = threadIdx.x;       // 0..511
    int c = np >> 2, sec = np & 3;
    float v = 0.f;
    if (k < 384) {
        if (sec < 3) {
            int t = k >> 7, kk = k & 127;
            const float* wm = Wmsg + ((long)t * HID + kk) * HID;
            const float* wi = Wih + (long)(sec * HID + c) * HID;
            float s = 0.f;
            for (int j = 0; j < HID; j++) s += wm[j] * wi[j];
            v = s;
        }
    } else {
        int kk = k - 384;
        if (sec == 0)      v = Whh[(long)c * HID + kk];
        else if (sec == 1) v = Whh[(long)(HID + c) * HID + kk];
        else if (sec == 3) v = Whh[(long)(2 * HID + c) * HID + kk];
    }
    int nb = np >> 5, nl = np & 31;
    int k16 = k >> 4, kgg = (k >> 3) & 1, e = k & 7;
    Bf[((((nb * 32 + k16) * 2 + kgg) * 32 + nl) << 3) + e] = f2bf(v);
}

__global__ __launch_bounds__(512) void k_build_bias(const float* __restrict__ bih,
                                                    const float* __restrict__ bhh,
                                                    const float* __restrict__ bmsg,
                                                    const float* __restrict__ Wih,
                                                    float* __restrict__ bbig,
                                                    float* __restrict__ Bdeg) {
    int np = threadIdx.x;      // 0..511 permuted
    int c = np >> 2, sec = np & 3;
    float b;
    if (sec == 0)      b = bih[c] + bhh[c];
    else if (sec == 1) b = bih[HID + c] + bhh[HID + c];
    else if (sec == 2) b = bih[2 * HID + c];
    else               b = bhh[2 * HID + c];
    bbig[np] = b;
    for (int t = 0; t < 3; t++) {
        float s = 0.f;
        if (sec < 3) {
            const float* wi = Wih + (long)(sec * HID + c) * HID;
            const float* bm = bmsg + t * HID;
            for (int j = 0; j < HID; j++) s += bm[j] * wi[j];
        }
        Bdeg[t * 512 + np] = s;
    }
}

// ---------------------------------------------------------------------------
// Aggregate: one WAVE per node, gather from compact Y [n][128], write A_cat
// into X cols 0..383 AND copy h (Y row) into X cols 384..511.
// ---------------------------------------------------------------------------
__global__ __launch_bounds__(256) void k_agg(const unsigned short* __restrict__ Y,
                                             unsigned short* __restrict__ X,
                                             const int* __restrict__ deg,
                                             const int* __restrict__ csr) {
    const int lane = threadIdx.x & 63;
    const long n = (long)blockIdx.x * 4 + (threadIdx.x >> 6);
    const int g = lane >> 4;
    const int c16 = lane & 15;
    const int l31 = lane & 31;

    int d[3], il[3];
#pragma unroll
    for (int t = 0; t < 3; t++) {
        int dt = deg[t * NN + n];
        d[t] = dt > DEG_CAP ? DEG_CAP : dt;
        il[t] = csr[((long)t * NN + n) * DEG_CAP + l31];
    }
#pragma unroll
    for (int t = 0; t < 3; t++) {
        float acc[8] = {0.f, 0.f, 0.f, 0.f, 0.f, 0.f, 0.f, 0.f};
        int rounds = (d[t] + 3) >> 2;
        for (int r = 0; r < rounds; r++) {
            int j = r * 4 + g;
            int idx = __shfl(il[t], j & 31);
            if (j < d[t]) {
                short8 v = *(const short8*)(Y + (long)idx * HID + c16 * 8);
#pragma unroll
                for (int q = 0; q < 8; q++) acc[q] += bf2f((unsigned short)v[q]);
            }
        }
#pragma unroll
        for (int q = 0; q < 8; q++) {
            acc[q] += __shfl_xor(acc[q], 16);
            acc[q] += __shfl_xor(acc[q], 32);
        }
        if (g == 0) {
            short8 o;
#pragma unroll
            for (int q = 0; q < 8; q++) o[q] = (short)f2bf(acc[q]);
            *(short8*)(X + n * XS + t * HID + c16 * 8) = o;
        }
    }
    if (g == 1) {   // h copy: Y row -> X cols 384..511
        short8 v = *(const short8*)(Y + n * HID + c16 * 8);
        *(short8*)(X + n * XS + 384 + c16 * 8) = v;
    }
}

// ---------------------------------------------------------------------------
// Fused GRU step v4 — m97-analog: BOTH operands via global_load_lds dbuf.
// Tile 128M x 256N (grid 2 x 782), 8 waves (2Mw x 4Nw), wave tile 64x64
// (acc[2][2] = 64 AGPR, ~116 unified regs -> 4 waves/SIMD, 2 blocks/CU at
// 48KB LDS). T3 minimum 2-phase loop: barrier (vmcnt drain) -> fire 3 DMA
// per wave into buf^1 -> 8 ds_read_b128 + 8 MFMA from buf. Loads never pass
// through registers -> no per-iteration VMEM register-wait (the stall that
// pinned R7-R15 at 13-18% MfmaUtil). B fragment-ordered (coalesced 1KB).
// Sec-minor N-perm -> block owns 64 complete channels; epilogue v2 in
// 8 x 16-row chunks through EX[16][264] overlay. Writes h ONLY to Y.
// ---------------------------------------------------------------------------
__global__ __launch_bounds__(512, 4) void k_gru_mfma(
        const unsigned short* __restrict__ X,
        const unsigned short* __restrict__ Y,
        unsigned short* __restrict__ Yw,
        const unsigned short* __restrict__ Bf,
        const float* __restrict__ bbig, const float* __restrict__ Bdeg,
        const int4* __restrict__ degp) {
    __shared__ char lds[49152];     // 2 x (A 8KB + B 16KB); EX overlays buf0

    const int tid = threadIdx.x;
    const int lane = tid & 63;
    const int wv = tid >> 6;        // 0..7
    const int wr = wv >> 2;         // 0..1 M-half
    const int wc = wv & 3;          // 0..3 N-quarter
    const int r31 = lane & 31;
    const int kg = lane >> 5;
    const int bn = blockIdx.x;      // 0..1 N-half (256 cols, 64 channels)
    const long row0 = (long)blockIdx.y * 128;

    f32x16 acc[2][2];
#pragma unroll
    for (int i = 0; i < 2; i++)
#pragma unroll
        for (int j = 0; j < 2; j++) acc[i][j] = (f32x16)(0.0f);

    // A src: frag f = wv -> mt = wv&3 (32-row group), k16l = wv>>2 (0..1)
    const char* pAsrc = (const char*)X + (row0 + (wv & 3) * 32 + r31) * 1024
                        + (wv >> 2) * 32 + kg * 16;
    // B src: wave stages nbl = wv (frag rows nb = bn*8 + wv), coalesced 1KB
    const char* pBsrc = (const char*)Bf + ((long)(bn * 8 + wv) * 32) * 1024
                        + lane * 16;

#define STAGE(BUFOFF, KS)                                                     \
    {                                                                         \
        gload16(pAsrc + (KS) * 64, lds + (BUFOFF) + wv * 1024);               \
        gload16(pBsrc + ((long)(KS) * 2 + 0) * 1024,                          \
                lds + (BUFOFF) + 8192 + (0 * 8 + wv) * 1024);                 \
        gload16(pBsrc + ((long)(KS) * 2 + 1) * 1024,                          \
                lds + (BUFOFF) + 8192 + (1 * 8 + wv) * 1024);                 \
    }

    STAGE(0, 0);

#pragma unroll
    for (int ks = 0; ks < 16; ks++) {
        const int cur = (ks & 1) * 24576;
        __syncthreads();                        // drains vmcnt: buf[cur] ready
        if (ks < 15) STAGE(24576 - cur, ks + 1);    // fire into other buf
        const char* Ab = lds + cur;
        const char* Bb = lds + cur + 8192;
#pragma unroll
        for (int k16l = 0; k16l < 2; k16l++) {
            short8 a0 = *(const short8*)(Ab + (k16l * 4 + wr * 2 + 0) * 1024 + lane * 16);
            short8 a1 = *(const short8*)(Ab + (k16l * 4 + wr * 2 + 1) * 1024 + lane * 16);
            short8 b0 = *(const short8*)(Bb + (k16l * 8 + wc * 2 + 0) * 1024 + lane * 16);
            short8 b1 = *(const short8*)(Bb + (k16l * 8 + wc * 2 + 1) * 1024 + lane * 16);
            acc[0][0] = MFMA(a0, b0, acc[0][0]);
            acc[0][1] = MFMA(a0, b1, acc[0][1]);
            acc[1][0] = MFMA(a1, b0, acc[1][0]);
            acc[1][1] = MFMA(a1, b1, acc[1][1]);
        }
    }
#undef STAGE

    // ---- epilogue: 8 chunks of 16 rows; EX = [16][264] f32 overlay ----
    float* EX = (float*)lds;
#pragma unroll
    for (int c = 0; c < 8; c++) {
        __syncthreads();
        if (wr == (c >> 2)) {                   // writer waves (4 of 8)
            const int mt = (c >> 1) & 1;
            const int q8 = (c & 1) * 8;
#pragma unroll
            for (int ct = 0; ct < 2; ct++) {
                const int col = wc * 64 + ct * 32 + r31;
#pragma unroll
                for (int rr = 0; rr < 8; rr++) {
                    int rwl = (rr & 3) + 8 * (rr >> 2) + 4 * kg;   // 0..15
                    EX[rwl * 264 + col] = acc[mt][ct][q8 + rr];
                }
            }
        }
        __syncthreads();
        {
            const int row16 = tid >> 5;         // 0..15
            const long grow = row0 + c * 16 + row16;
            int4 dg = degp[grow];
            float dgx = (float)dg.x, dgy = (float)dg.y, dgz = (float)dg.z;
#pragma unroll
            for (int i = 0; i < 2; i++) {
                const int chl = (tid & 31) + i * 32;    // local channel 0..63
                const int gch = bn * 64 + chl;          // global channel
                float4 v  = *(const float4*)(EX + row16 * 264 + chl * 4);
                float4 bb = *(const float4*)(bbig + bn * 256 + chl * 4);
                float4 q0 = *(const float4*)(Bdeg + bn * 256 + chl * 4);
                float4 q1 = *(const float4*)(Bdeg + 512 + bn * 256 + chl * 4);
                float4 q2 = *(const float4*)(Bdeg + 1024 + bn * 256 + chl * 4);
                float Sr = v.x + bb.x + dgx * q0.x + dgy * q1.x + dgz * q2.x;
                float Sz = v.y + bb.y + dgx * q0.y + dgy * q1.y + dgz * q2.y;
                float In = v.z + bb.z + dgx * q0.z + dgy * q1.z + dgz * q2.z;
                float Hn = v.w + bb.w;      // sec3 deg-bias is 0 by construction
                float rr = sigm(Sr);
                float zz = sigm(Sz);
                float tt = In + rr * Hn;
                float ee = __expf(2.f * tt);
                float nn = 1.f - 2.f / (ee + 1.f);
                float hv = (1.f - zz) * nn + zz * bf2f(Y[grow * HID + gch]);
                Yw[grow * HID + gch] = f2bf(hv);
            }
        }
    }
}

// ---------------------------------------------------------------------------
// Readout: out[g] += sigmoid(h@Wg.T+bg) * (h@Wp.T+bp). h from Y bf16.
// ---------------------------------------------------------------------------
__global__ __launch_bounds__(256) void k_readout(const unsigned short* __restrict__ Y,
                                                 const int* __restrict__ n2g,
                                                 const float* __restrict__ Wp,
                                                 const float* __restrict__ bp,
                                                 const float* __restrict__ Wg,
                                                 const float* __restrict__ bg,
                                                 float* __restrict__ out) {
    __shared__ float hs[32][132];
    __shared__ float Ws[64][129];
    int tid = threadIdx.x;
    long row0 = (long)blockIdx.x * 32;
    int rg = tid >> 5, cg = tid & 31;
    float acc[4][4];
#pragma unroll
    for (int r = 0; r < 4; r++)
#pragma unroll
        for (int c = 0; c < 4; c++) acc[r][c] = 0.f;

#pragma unroll
    for (int p = 0; p < 2; p++) {
        int e = p * 256 + tid;
        int r = e >> 4, c8 = e & 15;
        short8 v = *(const short8*)(Y + (row0 + r) * HID + c8 * 8);
#pragma unroll
        for (int j = 0; j < 8; j++) hs[r][c8 * 8 + j] = bf2f((unsigned short)v[j]);
    }
    for (int kc = 0; kc < 128; kc += 64) {
        __syncthreads();
#pragma unroll
        for (int p = 0; p < 8; p++) {
            int idx = p * 256 + tid;
            int j = idx >> 4, q = idx & 15;
            const float* Wsrc = (j < 64) ? Wp : Wg;
            float4 w = *(const float4*)&Wsrc[(j & 63) * HID + kc + q * 4];
            Ws[q * 4 + 0][j] = w.x;
            Ws[q * 4 + 1][j] = w.y;
            Ws[q * 4 + 2][j] = w.z;
            Ws[q * 4 + 3][j] = w.w;
        }
        __syncthreads();
#pragma unroll 8
        for (int k = 0; k < 64; k++) {
            float a[4], w[4];
#pragma unroll
            for (int r = 0; r < 4; r++) a[r] = hs[rg * 4 + r][kc + k];
#pragma unroll
            for (int c = 0; c < 4; c++) w[c] = Ws[k][cg + 32 * c];
#pragma unroll
            for (int r = 0; r < 4; r++)
#pragma unroll
                for (int c = 0; c < 4; c++) acc[r][c] += a[r] * w[c];
        }
    }
#pragma unroll
    for (int r = 0; r < 4; r++) {
        long row = row0 + rg * 4 + r;
        if (row < NN) {
            int g = n2g[row];
            float pv0 = acc[r][0] + bp[cg];
            float pv1 = acc[r][1] + bp[cg + 32];
            float gv0 = acc[r][2] + bg[cg];
            float gv1 = acc[r][3] + bg[cg + 32];
            atomicAdd(&out[g * EMB + cg],      pv0 * sigm(gv0));
            atomicAdd(&out[g * EMB + cg + 32], pv1 * sigm(gv1));
        }
    }
}

// ---------------------------------------------------------------------------
extern "C" void kernel_launch(void* const* d_in, const int* in_sizes, int n_in,
                              void* d_out, int out_size, void* d_ws, size_t ws_size,
                              hipStream_t stream) {
    const float* node_features = (const float*)d_in[0];
    const int*   edge_index    = (const int*)d_in[1];
    const int*   n2g           = (const int*)d_in[2];
    const float* W_msg         = (const float*)d_in[3];
    const float* b_msg         = (const float*)d_in[4];
    const float* W_ih          = (const float*)d_in[5];
    const float* W_hh          = (const float*)d_in[6];
    const float* b_ih          = (const float*)d_in[7];
    const float* b_hh          = (const float*)d_in[8];
    const float* W_proj        = (const float*)d_in[9];
    const float* b_proj        = (const float*)d_in[10];
    const float* W_gate        = (const float*)d_in[11];
    const float* b_gate        = (const float*)d_in[12];

    char* ws = (char*)d_ws;
    unsigned short* X    = (unsigned short*)(ws);                 // 102,498,304 B
    unsigned short* Y    = (unsigned short*)(ws + 102498304);     //  25,624,576 B
    unsigned short* Bf   = (unsigned short*)(ws + 128122880);     //     524,288 B
    float*          bbig = (float*)         (ws + 128647168);     //       2,048 B
    float*          Bdeg = (float*)         (ws + 128649216);     //       6,144 B
    int4*           degp = (int4*)          (ws + 128655360);     //   1,601,536 B
    int*            deg  = (int*)           (ws + 130256896);     //   1,200,000 B
    int*            csr  = (int*)           (ws + 131456896);     //  38,400,000 B -> 169,856,896

    float* out = (float*)d_out;

    hipMemsetAsync(out, 0, (size_t)NG * EMB * sizeof(float), stream);
    hipMemsetAsync(deg, 0, (size_t)3 * NN * sizeof(int), stream);

    k_init<<<dim3((NNP * HID) / 256), dim3(256), 0, stream>>>(node_features, Y);
    k_build_csr<<<dim3((3 * NE + 255) / 256), dim3(256), 0, stream>>>(edge_index, deg, csr);
    k_pack_deg<<<dim3(NNP / 256), dim3(256), 0, stream>>>(deg, degp);
    k_build_w<<<dim3(512), dim3(512), 0, stream>>>(W_msg, W_ih, W_hh, Bf);
    k_build_bias<<<dim3(1), dim3(512), 0, stream>>>(b_ih, b_hh, b_msg, W_ih, bbig, Bdeg);

    for (int step = 0; step < 4; step++) {
        k_agg<<<dim3(NN / 4), dim3(256), 0, stream>>>(Y, X, deg, csr);
        k_gru_mfma<<<dim3(2, NNP / 128), dim3(512), 0, stream>>>(X, Y, Y, Bf,
                                                                 bbig, Bdeg, degp);
    }
    k_readout<<<dim3(NN / 32), dim3(256), 0, stream>>>(Y, n2g, W_proj, b_proj,
                                                       W_gate, b_gate, out);
}